// Round 1
// baseline (2918.064 us; speedup 1.0000x reference)
//
#include <hip/hip_runtime.h>

// LSTM: B=64, S=512, D=H=512. Persistent-kernel design:
//  - 128 WGs = 4 batch-groups (16 rows) x 32 h-slices (16 h-cols -> 64 gate cols)
//  - Per WG: B = [W;U] slice (1024 x 64) bf16 resident in LDS (128 KB, swizzled)
//  - Per step: stage x_t -> LDS A, x-GEMM, wait group flag, stage h_{t-1} -> A,
//    h-GEMM, gate exchange via LDS, elementwise (fp32 c-state in regs),
//    write h slice to global double buffer, release-bump group counter.

#define NGROUP 4
#define NSLICE 32
#define GROWS  16
#define SCOLS  16
#define DIM    512
#define HID    512
#define SEQ    512
#define NTHR   256
#define NWG    (NGROUP*NSLICE)

#define AOFF 0
#define BOFF 16384
#define LDS_BYTES (BOFF + 64*2048)        // 16 KB A-stage + 128 KB B = 147456

#define WS_CNT_BYTES 1024
#define HBUF_ELEMS   (2*NGROUP*GROWS*HID) // 65536 bf16 elems (2 parities x 64 x 512)
#define WS_NEED      (WS_CNT_BYTES + HBUF_ELEMS*2)

typedef float f32x4  __attribute__((ext_vector_type(4)));
typedef short bf16x8 __attribute__((ext_vector_type(8)));

__device__ __forceinline__ unsigned short f2bf(float f){
  union { float f; unsigned u; } v; v.f = f;
  unsigned r = v.u + 0x7fffu + ((v.u >> 16) & 1u);   // RNE
  return (unsigned short)(r >> 16);
}
__device__ __forceinline__ float sigm(float x){ return 1.0f/(1.0f + __expf(-x)); }
__device__ __forceinline__ float tanh_f(float x){
  float e = __expf(-2.0f * fabsf(x));
  float t = (1.0f - e)/(1.0f + e);
  return x < 0.0f ? -t : t;
}

__global__ void zero_ws_kernel(uint4* p, int n4){
  int i = blockIdx.x*blockDim.x + threadIdx.x;
  uint4 z; z.x=0u; z.y=0u; z.z=0u; z.w=0u;
  if (i < n4) p[i] = z;
}

__global__ __launch_bounds__(NTHR, 1) void lstm_persistent(
  const float* __restrict__ x,
  const float* __restrict__ W0, const float* __restrict__ W1,
  const float* __restrict__ W2, const float* __restrict__ W3,
  const float* __restrict__ U0, const float* __restrict__ U1,
  const float* __restrict__ U2, const float* __restrict__ U3,
  const float* __restrict__ b0, const float* __restrict__ b1,
  const float* __restrict__ b2, const float* __restrict__ b3,
  float* __restrict__ out,
  unsigned* __restrict__ cnt,
  unsigned short* __restrict__ hbuf)
{
  __shared__ __align__(16) char smem[LDS_BYTES];
  const int tid = threadIdx.x;
  const int bid = blockIdx.x;
  const int g = bid >> 5;       // batch group 0..3 (rows 16g..16g+15)
  const int s = bid & 31;       // h-slice 0..31 (h cols 16s..16s+15)
  const int w = tid >> 6;       // wave = gate (i,f,o,c)
  const int l = tid & 63;

  // ---- one-time: stage B = [W;U] slice into LDS (col-major, swizzled) ----
  {
    const int c    = tid & 63;          // local gate-col 0..63 (gate*16 + cc)
    const int kq   = tid >> 6;          // k quarter
    const int gate = c >> 4;
    const int cc   = c & 15;
    const int col  = s*SCOLS + cc;
    const float* Wsrc = (gate==0)?W0:(gate==1)?W1:(gate==2)?W2:W3;
    const float* Usrc = (gate==0)?U0:(gate==1)?U1:(gate==2)?U2:U3;
    const unsigned swz = (unsigned)((c & 7) << 4);
    char* Bp = &smem[BOFF + c*2048];
    #pragma unroll 4
    for (int k = kq*256; k < kq*256 + 256; ++k){
      float v = (k < DIM) ? Wsrc[(size_t)k*HID + col]
                          : Usrc[(size_t)(k-DIM)*HID + col];
      *(unsigned short*)(Bp + (((unsigned)(k*2)) ^ swz)) = f2bf(v);
    }
  }

  // per-thread elementwise constants (thread -> (row er, slice-col ec))
  const int er = tid >> 4;
  const int ec = tid & 15;
  const int ecol = s*SCOLS + ec;
  const float bi = b0[ecol], bff = b1[ecol], bo = b2[ecol], bc = b3[ecol];
  float cstate = 0.0f;
  float hout   = 0.0f;

  // per-lane MFMA fragment constants
  const int arow = l & 15;
  const int qh   = l >> 4;
  const unsigned swzA = (unsigned)((arow & 7) << 4);
  const int bcol = w*16 + arow;
  const unsigned swzB = (unsigned)((bcol & 7) << 4);   // (bcol&7)==(arow&7): consistent k-perm
  const char* Abase = &smem[AOFF + arow*1024];
  const char* Bbase = &smem[BOFF + bcol*2048];
  float* gatesLds = (float*)&smem[AOFF];               // alias, used post-GEMM only

  // staging constants (thread -> (row sr, 32-elem block sdb))
  const int sr  = tid >> 4;
  const int sdb = tid & 15;
  const unsigned swzS = (unsigned)((sr & 7) << 4);
  char* Arow = &smem[AOFF + sr*1024];

  unsigned* mycnt = &cnt[g*32];

  __syncthreads();

#define GEMM_STEP(QA, QB, ACC) do { \
    bf16x8 a_ = *(const bf16x8*)(Abase + (((unsigned)((QA)*64 + qh*16)) ^ swzA)); \
    bf16x8 b_ = *(const bf16x8*)(Bbase + (((unsigned)((QB)*64 + qh*16)) ^ swzB)); \
    ACC = __builtin_amdgcn_mfma_f32_16x16x32_bf16(a_, b_, ACC, 0, 0, 0); \
  } while(0)

  for (int t = 0; t < SEQ; ++t){
    // 1) stage x[:, t, :] -> A (fp32 -> bf16), before the flag wait
    {
      const float* xp = x + ((size_t)(g*GROWS + sr)*SEQ + (size_t)t)*DIM + sdb*32;
      #pragma unroll
      for (int j = 0; j < 4; ++j){
        f32x4 u = *(const f32x4*)(xp + j*8);
        f32x4 v = *(const f32x4*)(xp + j*8 + 4);
        bf16x8 o8;
        o8[0]=(short)f2bf(u[0]); o8[1]=(short)f2bf(u[1]);
        o8[2]=(short)f2bf(u[2]); o8[3]=(short)f2bf(u[3]);
        o8[4]=(short)f2bf(v[0]); o8[5]=(short)f2bf(v[1]);
        o8[6]=(short)f2bf(v[2]); o8[7]=(short)f2bf(v[3]);
        *(bf16x8*)(Arow + (((unsigned)(sdb*64 + j*16)) ^ swzS)) = o8;
      }
    }
    __syncthreads();

    f32x4 acc0 = {0.f,0.f,0.f,0.f}, acc1 = {0.f,0.f,0.f,0.f};
    f32x4 acc2 = {0.f,0.f,0.f,0.f}, acc3 = {0.f,0.f,0.f,0.f};

    // 2) x-half GEMM (B rows 0..511 = W)
    #pragma unroll
    for (int q4 = 0; q4 < 4; ++q4){
      GEMM_STEP(q4*4+0, q4*4+0, acc0);
      GEMM_STEP(q4*4+1, q4*4+1, acc1);
      GEMM_STEP(q4*4+2, q4*4+2, acc2);
      GEMM_STEP(q4*4+3, q4*4+3, acc3);
    }

    // 3) wait for all 32 producers of h_{t-1}
    if (t > 0 && tid == 0){
      const unsigned target = (unsigned)(32*t);
      while (__hip_atomic_load(mycnt, __ATOMIC_ACQUIRE, __HIP_MEMORY_SCOPE_AGENT) < target)
        __builtin_amdgcn_s_sleep(1);
    }
    __syncthreads();

    // 4) stage h_{t-1} -> A (bf16 passthrough), reuses x region
    {
      const unsigned short* hsrc =
        hbuf + ((size_t)((t&1)*NGROUP + g)*GROWS + sr)*HID + sdb*32;
      #pragma unroll
      for (int j = 0; j < 4; ++j){
        bf16x8 hv = *(const bf16x8*)(hsrc + j*8);
        *(bf16x8*)(Arow + (((unsigned)(sdb*64 + j*16)) ^ swzS)) = hv;
      }
    }
    __syncthreads();

    // 5) h-half GEMM (B rows 512..1023 = U)
    #pragma unroll
    for (int q4 = 0; q4 < 4; ++q4){
      GEMM_STEP(q4*4+0, q4*4+16, acc0);
      GEMM_STEP(q4*4+1, q4*4+17, acc1);
      GEMM_STEP(q4*4+2, q4*4+18, acc2);
      GEMM_STEP(q4*4+3, q4*4+19, acc3);
    }
    __syncthreads();   // A fully consumed -> safe to alias gates

    // 6) gate exchange: wave w writes its 16x16 tile (C/D: col=l&15, row=4*qh+rr)
    f32x4 accs = (acc0 + acc1) + (acc2 + acc3);
    #pragma unroll
    for (int rr = 0; rr < 4; ++rr)
      gatesLds[(qh*4 + rr)*64 + w*16 + arow] = accs[rr];
    __syncthreads();

    // 7) elementwise LSTM cell, fp32 state
    {
      float gi = gatesLds[er*64 +  0 + ec] + bi;
      float gf = gatesLds[er*64 + 16 + ec] + bff;
      float go = gatesLds[er*64 + 32 + ec] + bo;
      float gc = gatesLds[er*64 + 48 + ec] + bc;
      float ig = sigm(gi), fg = sigm(gf), og = sigm(go), ct = tanh_f(gc);
      cstate = fg*cstate + ig*ct;
      hout = og * tanh_f(cstate);
      hbuf[((size_t)(((t+1)&1)*NGROUP + g)*GROWS + er)*HID + s*SCOLS + ec] = f2bf(hout);
    }
    __syncthreads();

    // 8) release: make h stores visible device-wide, bump group counter
    if (tid == 0)
      __hip_atomic_fetch_add(mycnt, 1u, __ATOMIC_RELEASE, __HIP_MEMORY_SCOPE_AGENT);
  }

  // epilogue: final h (fp32, pre-bf16-rounding value)
  out[(size_t)(g*GROWS + er)*HID + s*SCOLS + ec] = hout;
#undef GEMM_STEP
}

extern "C" void kernel_launch(void* const* d_in, const int* in_sizes, int n_in,
                              void* d_out, int out_size, void* d_ws, size_t ws_size,
                              hipStream_t stream)
{
  (void)in_sizes; (void)n_in; (void)out_size;
  if (ws_size < (size_t)WS_NEED) return;

  const float* x  = (const float*)d_in[0];
  const float* W0 = (const float*)d_in[1];
  const float* W1 = (const float*)d_in[2];
  const float* W2 = (const float*)d_in[3];
  const float* W3 = (const float*)d_in[4];
  const float* U0 = (const float*)d_in[5];
  const float* U1 = (const float*)d_in[6];
  const float* U2 = (const float*)d_in[7];
  const float* U3 = (const float*)d_in[8];
  const float* b0 = (const float*)d_in[9];
  const float* b1 = (const float*)d_in[10];
  const float* b2 = (const float*)d_in[11];
  const float* b3 = (const float*)d_in[12];
  float* out = (float*)d_out;

  unsigned* cnt = (unsigned*)d_ws;
  unsigned short* hbuf = (unsigned short*)((char*)d_ws + WS_CNT_BYTES);

  const int n4 = WS_NEED / 16;
  zero_ws_kernel<<<dim3((n4 + 255)/256), dim3(256), 0, stream>>>((uint4*)d_ws, n4);
  lstm_persistent<<<dim3(NWG), dim3(NTHR), 0, stream>>>(
      x, W0,W1,W2,W3, U0,U1,U2,U3, b0,b1,b2,b3, out, cnt, hbuf);
}